// Round 6
// baseline (477.634 us; speedup 1.0000x reference)
//
#include <hip/hip_runtime.h>
#include <hip/hip_cooperative_groups.h>
#include <math.h>

namespace cg = cooperative_groups;

#define C_ 256
#define R_ 16
#define B_ 8
#define H_ 128
#define W_ 128
#define HW_ (H_ * W_)
#define CG_ 8            // channel groups
#define CPG_ (C_ / CG_)  // 32 channels per group
#define NCHUNK_ 16       // pixel chunks per image (1024 px each)
#define TS_ 38
#define SHF_ (2 * TS_ * TS_)  // 2888 floats shared buffer (union across phases)

typedef float f4_ __attribute__((ext_vector_type(4)));

__device__ __forceinline__ float sigmoidf_(float z) {
    return 1.0f / (1.0f + __expf(-z));
}

__device__ __forceinline__ int reflect_(int g) {
    if (g < 0) g = -g;
    if (g > 127) g = 254 - g;
    return g;
}

__global__ void __launch_bounds__(256, 4)
fused_all(const float* __restrict__ x, const float* __restrict__ dct_w,
          const float* __restrict__ w1, const float* __restrict__ b1,
          const float* __restrict__ w2, const float* __restrict__ b2,
          const float* __restrict__ alphap, const float* __restrict__ lapp,
          float* __restrict__ out,
          float* __restrict__ ptemp, float* __restrict__ psum, float* __restrict__ pmax,
          float* __restrict__ heat, float* __restrict__ att) {
    __shared__ float sh[SHF_];
    int tid = threadIdx.x;
    int bid = blockIdx.x;

    // ---------- Phase 1: single x-pass -> partial temp + per-(b,chunk,c) stats.
    {
        float* sm_   = sh;          // 32
        float* pmred = sh + 32;     // 8*32
        float* lsum  = sh + 288;    // 16*33
        float* lmax  = sh + 816;    // 16*33 (ends at 1344)
        int b = bid >> 7, chunk = (bid >> 3) & 15, cg_ = bid & 7;

        {   // m[c] slice for this channel group from L2-resident dct_w
            int c_l = tid & 31, oc = tid >> 5;
            const float* p = dct_w + cg_ * CPG_ + c_l;
            float pm = 0.0f;
            for (int k = 0; k < 32; ++k) pm += p[(oc * 32 + k) * C_];
            pmred[oc * 32 + c_l] = pm;
        }
        __syncthreads();
        if (tid < CPG_) {
            float t = 0.0f;
            for (int o = 0; o < 8; ++o) t += pmred[o * 32 + tid];
            sm_[tid] = t * (1.0f / C_);
        }
        __syncthreads();

        int pix = chunk * 1024 + tid * 4;
        const f4_* px = (const f4_*)(x + (size_t)(b * C_ + cg_ * CPG_) * HW_ + pix);
        int lane = tid & 63, wid = tid >> 6;
        int grp = (wid << 2) | (lane >> 4);
        bool writer = (lane & 15) == 0;

        f4_ acc = {0.0f, 0.0f, 0.0f, 0.0f};
#pragma unroll 2
        for (int c = 0; c < CPG_; ++c) {
            f4_ v = px[(size_t)c * (HW_ / 4)];
            float w = sm_[c];
            acc.x = fmaf(w, v.x, acc.x);
            acc.y = fmaf(w, v.y, acc.y);
            acc.z = fmaf(w, v.z, acc.z);
            acc.w = fmaf(w, v.w, acc.w);
            float s = (v.x + v.y) + (v.z + v.w);
            float mx = fmaxf(fmaxf(v.x, v.y), fmaxf(v.z, v.w));
            for (int mo = 8; mo >= 1; mo >>= 1) {
                s += __shfl_xor(s, mo, 16);
                mx = fmaxf(mx, __shfl_xor(mx, mo, 16));
            }
            if (writer) { lsum[grp * 33 + c] = s; lmax[grp * 33 + c] = mx; }
        }
        *(f4_*)(ptemp + (size_t)(cg_ * B_ + b) * HW_ + pix) = acc;
        __syncthreads();

        if (tid < CPG_) {
            float S = 0.0f, M = -3.402823466e+38f;
            for (int g = 0; g < 16; ++g) {
                S += lsum[g * 33 + tid];
                M = fmaxf(M, lmax[g * 33 + tid]);
            }
            psum[(size_t)(b * NCHUNK_ + chunk) * C_ + cg_ * CPG_ + tid] = S;
            pmax[(size_t)(b * NCHUNK_ + chunk) * C_ + cg_ * CPG_ + tid] = M;
        }
    }
    __threadfence();
    cg::this_grid().sync();

    // ---------- Phase 2: blocks 0..127 heat tiles; 128..135 SE MLP.
    if (bid < 128) {
        float* sA = sh;
        float* sB = sh + TS_ * TS_;
        int b = bid >> 4;
        int tile = bid & 15;
        int tr = (tile >> 2) * 32, tc = (tile & 3) * 32;
        for (int i = tid; i < TS_ * TS_; i += 256) {
            int lh = i / TS_, lw = i % TS_;
            int gh = reflect_(tr + lh - 3);
            int gw = reflect_(tc + lw - 3);
            size_t a = (size_t)gh * W_ + gw + (size_t)b * HW_;
            float v = 0.0f;
            for (int cg_ = 0; cg_ < CG_; ++cg_) v += ptemp[(size_t)cg_ * B_ * HW_ + a];
            sA[i] = v;
        }
        float alpha = *alphap;
        float l0 = lapp[0], l1 = lapp[1], l2 = lapp[2],
              l3 = lapp[3], l4 = lapp[4], l5 = lapp[5],
              l6 = lapp[6], l7 = lapp[7], l8 = lapp[8];
        __syncthreads();
#define DIFF(src, lh, lw)                                                              \
        fmaf(alpha,                                                                    \
             l0 * src[(lh - 1) * TS_ + lw - 1] + l1 * src[(lh - 1) * TS_ + lw] +       \
             l2 * src[(lh - 1) * TS_ + lw + 1] + l3 * src[lh * TS_ + lw - 1] +         \
             l4 * src[lh * TS_ + lw] + l5 * src[lh * TS_ + lw + 1] +                   \
             l6 * src[(lh + 1) * TS_ + lw - 1] + l7 * src[(lh + 1) * TS_ + lw] +       \
             l8 * src[(lh + 1) * TS_ + lw + 1],                                        \
             src[lh * TS_ + lw])
        for (int i = tid; i < 36 * 36; i += 256) {
            int lh = i / 36 + 1, lw = i % 36 + 1;
            sB[lh * TS_ + lw] = DIFF(sA, lh, lw);
        }
        __syncthreads();
        for (int i = tid; i < 34 * 34; i += 256) {
            int lh = i / 34 + 2, lw = i % 34 + 2;
            sA[lh * TS_ + lw] = DIFF(sB, lh, lw);
        }
        __syncthreads();
        float* hb = heat + b * HW_;
        for (int i = tid; i < 32 * 32; i += 256) {
            int lh = i / 32 + 3, lw = i % 32 + 3;
            float v = DIFF(sA, lh, lw);
            hb[(tr + lh - 3) * W_ + (tc + lw - 3)] = sigmoidf_(v);
        }
#undef DIFF
    } else if (bid < 136) {
        float* sa = sh;
        float* sx = sh + 256;
        float* ha = sh + 512;
        float* hm = sh + 528;
        int b = bid - 128;
        float S = 0.0f, M = -3.402823466e+38f;
        for (int ch = 0; ch < NCHUNK_; ++ch) {
            S += psum[(size_t)(b * NCHUNK_ + ch) * C_ + tid];
            M = fmaxf(M, pmax[(size_t)(b * NCHUNK_ + ch) * C_ + tid]);
        }
        sa[tid] = S * (1.0f / HW_);
        sx[tid] = M;
        __syncthreads();
        if (tid < 2 * R_) {
            int j = tid & (R_ - 1);
            bool isMax = tid >= R_;
            const float* y = isMax ? sx : sa;
            float s = b1[j];
            for (int c = 0; c < C_; ++c) s = fmaf(w1[j * C_ + c], y[c], s);
            s = fmaxf(s, 0.0f);
            (isMax ? hm : ha)[j] = s;
        }
        __syncthreads();
        float s1 = b2[tid], s2 = s1;
        for (int j = 0; j < R_; ++j) {
            float w = w2[tid * R_ + j];
            s1 = fmaf(w, ha[j], s1);
            s2 = fmaf(w, hm[j], s2);
        }
        att[b * C_ + tid] = sigmoidf_(s1) + sigmoidf_(s2);
    }
    __threadfence();
    cg::this_grid().sync();

    // ---------- Phase 3: out = x * sigmoid(att[b,c] * heat[b,hw]), grid-strided.
    for (int j = bid; j < 4096; j += 1024) {
        int bc = j >> 1, half = j & 1;
        int b = bc >> 8;
        float a = att[bc];
        size_t base = (size_t)bc * HW_ + half * (HW_ / 2);
        const f4_* px = (const f4_*)(x + base);
        const f4_* ph = (const f4_*)(heat + b * HW_ + half * (HW_ / 2));
        f4_* po = (f4_*)(out + base);
        for (int i = tid; i < HW_ / 8; i += 256) {
            f4_ v = px[i];
            f4_ h = ph[i];
            f4_ r;
            r.x = v.x * sigmoidf_(a * h.x);
            r.y = v.y * sigmoidf_(a * h.y);
            r.z = v.z * sigmoidf_(a * h.z);
            r.w = v.w * sigmoidf_(a * h.w);
            __builtin_nontemporal_store(r, &po[i]);
        }
    }
}

extern "C" void kernel_launch(void* const* d_in, const int* in_sizes, int n_in,
                              void* d_out, int out_size, void* d_ws, size_t ws_size,
                              hipStream_t stream) {
    const float* x     = (const float*)d_in[0];
    const float* dct_w = (const float*)d_in[1];
    const float* w1    = (const float*)d_in[2];
    const float* b1    = (const float*)d_in[3];
    const float* w2    = (const float*)d_in[4];
    const float* b2    = (const float*)d_in[5];
    const float* alpha = (const float*)d_in[6];
    const float* lap   = (const float*)d_in[7];
    float* out = (float*)d_out;

    float* ws    = (float*)d_ws;
    float* psum  = ws;                      // 32768
    float* pmax  = ws + 32768;              // 32768
    float* att   = ws + 65536;              // 2048
    float* heat  = ws + 69632;              // 131072 (padded region)
    float* ptemp = ws + 200704;             // 8*8*16384 = 1048576

    void* args[] = {(void*)&x, (void*)&dct_w, (void*)&w1, (void*)&b1, (void*)&w2,
                    (void*)&b2, (void*)&alpha, (void*)&lap, (void*)&out,
                    (void*)&ptemp, (void*)&psum, (void*)&pmax, (void*)&heat, (void*)&att};
    hipLaunchCooperativeKernel((const void*)fused_all, dim3(1024), dim3(256),
                               args, 0, stream);
}

// Round 7
// 79.026 us; speedup vs baseline: 6.0440x; 6.0440x over previous
//
#include <hip/hip_runtime.h>
#include <math.h>

#define C_ 256
#define R_ 16
#define B_ 8
#define H_ 128
#define W_ 128
#define HW_ (H_ * W_)
#define CG_ 8            // channel groups in k1
#define CPG_ (C_ / CG_)  // 32 channels per group
#define NCHUNK_ 16       // pixel chunks per image in k1

typedef float f4_ __attribute__((ext_vector_type(4)));

__device__ __forceinline__ float sigmoidf_(float z) {
    return 1.0f / (1.0f + __expf(-z));
}

__device__ __forceinline__ int reflect_(int g) {
    if (g < 0) g = -g;
    if (g > 127) g = 254 - g;
    return g;
}

// Single x-pass. Grid 1024 = (b, chunk, cg). Block reads 32 channels x 1024
// pixels (128 KiB) as float4, computes its own m[c] slice from L2-resident
// dct_w, emits partial temp (per cg) and per-(b,chunk,c) sum/max partials.
__global__ void k1_stats_temp(const float* __restrict__ x, const float* __restrict__ dct_w,
                              float* __restrict__ ptemp,
                              float* __restrict__ psum, float* __restrict__ pmax) {
    __shared__ float sm_[CPG_];
    __shared__ float pmred[8][CPG_];
    __shared__ float lsum[16][CPG_ + 1];
    __shared__ float lmax[16][CPG_ + 1];
    int tid = threadIdx.x;
    int bid = blockIdx.x;
    int b = bid >> 7, chunk = (bid >> 3) & 15, cg = bid & 7;

    {   // m[c] slice for this channel group from L2-resident dct_w
        int c_l = tid & 31, oc = tid >> 5;
        const float* p = dct_w + cg * CPG_ + c_l;
        float pm = 0.0f;
        for (int k = 0; k < 32; ++k) pm += p[(oc * 32 + k) * C_];
        pmred[oc][c_l] = pm;
    }
    __syncthreads();
    if (tid < CPG_) {
        float t = 0.0f;
        for (int o = 0; o < 8; ++o) t += pmred[o][tid];
        sm_[tid] = t * (1.0f / C_);
    }
    __syncthreads();

    int pix = chunk * 1024 + tid * 4;
    const f4_* px = (const f4_*)(x + (size_t)(b * C_ + cg * CPG_) * HW_ + pix);
    int lane = tid & 63, wid = tid >> 6;
    int grp = (wid << 2) | (lane >> 4);
    bool writer = (lane & 15) == 0;

    f4_ acc = {0.0f, 0.0f, 0.0f, 0.0f};
#pragma unroll 4
    for (int c = 0; c < CPG_; ++c) {
        f4_ v = px[(size_t)c * (HW_ / 4)];
        float w = sm_[c];
        acc.x = fmaf(w, v.x, acc.x);
        acc.y = fmaf(w, v.y, acc.y);
        acc.z = fmaf(w, v.z, acc.z);
        acc.w = fmaf(w, v.w, acc.w);
        float s = (v.x + v.y) + (v.z + v.w);
        float mx = fmaxf(fmaxf(v.x, v.y), fmaxf(v.z, v.w));
        for (int mo = 8; mo >= 1; mo >>= 1) {
            s += __shfl_xor(s, mo, 16);
            mx = fmaxf(mx, __shfl_xor(mx, mo, 16));
        }
        if (writer) { lsum[grp][c] = s; lmax[grp][c] = mx; }
    }
    *(f4_*)(ptemp + (size_t)(cg * B_ + b) * HW_ + pix) = acc;
    __syncthreads();

    if (tid < CPG_) {
        float S = 0.0f, M = -3.402823466e+38f;
        for (int g = 0; g < 16; ++g) {
            S += lsum[g][tid];
            M = fmaxf(M, lmax[g][tid]);
        }
        psum[(size_t)(b * NCHUNK_ + chunk) * C_ + cg * CPG_ + tid] = S;
        pmax[(size_t)(b * NCHUNK_ + chunk) * C_ + cg * CPG_ + tid] = M;
    }
}

// Grid 1024 = (b, row). Per block: heat for its row (7-row halo, reflect,
// 3 shrinking diffusion steps; W-reflect applied per step = exact), redundant
// stats-reduce + SE-MLP -> att[256], then out = x * sigmoid(att*heat) for the
// row across all 256 channels (nt-stores; x row reads are L3-resident).
__global__ void __launch_bounds__(256)
k2_fused(const float* __restrict__ x, const float* __restrict__ ptemp,
         const float* __restrict__ psum, const float* __restrict__ pmax,
         const float* __restrict__ w1, const float* __restrict__ b1,
         const float* __restrict__ w2, const float* __restrict__ b2,
         const float* __restrict__ alphap, const float* __restrict__ lapp,
         float* __restrict__ out) {
    __shared__ float sA[7 * W_];
    __shared__ float sB[5 * W_];
    __shared__ float hrow[W_];
    __shared__ float att_s[C_], savg[C_], smax_[C_], ha[R_], hm[R_];
    int tid = threadIdx.x;
    int b = blockIdx.x >> 7, r = blockIdx.x & 127;

    // 7 temp rows (reflected), summing the 8 k1 partials (L2-resident).
    for (int i = tid; i < 7 * W_; i += 256) {
        int lr = i >> 7, col = i & 127;
        int gr = reflect_(r - 3 + lr);
        size_t a = (size_t)b * HW_ + gr * W_ + col;
        float v = 0.0f;
#pragma unroll
        for (int cg = 0; cg < CG_; ++cg) v += ptemp[(size_t)cg * (B_ * HW_) + a];
        sA[i] = v;
    }
    // per-channel stats reduce (one channel per thread)
    {
        float S = 0.0f, M = -3.402823466e+38f;
        for (int ch = 0; ch < NCHUNK_; ++ch) {
            S += psum[(size_t)(b * NCHUNK_ + ch) * C_ + tid];
            M = fmaxf(M, pmax[(size_t)(b * NCHUNK_ + ch) * C_ + tid]);
        }
        savg[tid] = S * (1.0f / HW_);
        smax_[tid] = M;
    }
    float alpha = *alphap;
    float l0 = lapp[0], l1 = lapp[1], l2 = lapp[2],
          l3 = lapp[3], l4 = lapp[4], l5 = lapp[5],
          l6 = lapp[6], l7 = lapp[7], l8 = lapp[8];
    __syncthreads();

#define DIFF(src, lr, col, cm, cp)                                                     \
    fmaf(alpha,                                                                        \
         l0 * src[(lr - 1) * W_ + cm] + l1 * src[(lr - 1) * W_ + col] +                \
         l2 * src[(lr - 1) * W_ + cp] + l3 * src[lr * W_ + cm] +                       \
         l4 * src[lr * W_ + col] + l5 * src[lr * W_ + cp] +                            \
         l6 * src[(lr + 1) * W_ + cm] + l7 * src[(lr + 1) * W_ + col] +                \
         l8 * src[(lr + 1) * W_ + cp],                                                 \
         src[lr * W_ + col])

    // step 1: rows 1..5 of sA -> sB rows 0..4
    for (int i = tid; i < 5 * W_; i += 256) {
        int lr = (i >> 7) + 1, col = i & 127;
        int cm = col ? col - 1 : 1;
        int cp = (col < 127) ? col + 1 : 126;
        sB[(lr - 1) * W_ + col] = DIFF(sA, lr, col, cm, cp);
    }
    __syncthreads();
    // step 2: rows 1..3 of sB -> sA rows 0..2
    for (int i = tid; i < 3 * W_; i += 256) {
        int lr = (i >> 7) + 1, col = i & 127;
        int cm = col ? col - 1 : 1;
        int cp = (col < 127) ? col + 1 : 126;
        sA[(lr - 1) * W_ + col] = DIFF(sB, lr, col, cm, cp);
    }
    __syncthreads();
    // step 3: center row -> heat
    if (tid < W_) {
        int col = tid;
        int cm = col ? col - 1 : 1;
        int cp = (col < 127) ? col + 1 : 126;
        hrow[col] = sigmoidf_(DIFF(sA, 1, col, cm, cp));
    }
#undef DIFF

    // SE MLP hidden layer (32 threads: 16 avg + 16 max)
    if (tid < 2 * R_) {
        int j = tid & (R_ - 1);
        bool isMax = tid >= R_;
        const float* y = isMax ? smax_ : savg;
        float s = b1[j];
        for (int c = 0; c < C_; ++c) s = fmaf(w1[j * C_ + c], y[c], s);
        s = fmaxf(s, 0.0f);
        (isMax ? hm : ha)[j] = s;
    }
    __syncthreads();
    {
        float s1 = b2[tid], s2 = s1;
        for (int j = 0; j < R_; ++j) {
            float w = w2[tid * R_ + j];
            s1 = fmaf(w, ha[j], s1);
            s2 = fmaf(w, hm[j], s2);
        }
        att_s[tid] = sigmoidf_(s1) + sigmoidf_(s2);
    }
    __syncthreads();

    // out for this row across all 256 channels: 8 channels x 32 f4-cols per iter
    size_t xbase = (size_t)b * C_ * HW_ + (size_t)r * W_;
    int c0 = tid >> 5, col4 = tid & 31;
    const f4_* hp = (const f4_*)hrow;
    f4_ h = hp[col4];
#pragma unroll 4
    for (int cb = 0; cb < 32; ++cb) {
        int c = cb * 8 + c0;
        size_t off = xbase + (size_t)c * HW_ + col4 * 4;
        f4_ v = *(const f4_*)(x + off);
        float a = att_s[c];
        f4_ o;
        o.x = v.x * sigmoidf_(a * h.x);
        o.y = v.y * sigmoidf_(a * h.y);
        o.z = v.z * sigmoidf_(a * h.z);
        o.w = v.w * sigmoidf_(a * h.w);
        __builtin_nontemporal_store(o, (f4_*)(out + off));
    }
}

extern "C" void kernel_launch(void* const* d_in, const int* in_sizes, int n_in,
                              void* d_out, int out_size, void* d_ws, size_t ws_size,
                              hipStream_t stream) {
    const float* x     = (const float*)d_in[0];
    const float* dct_w = (const float*)d_in[1];
    const float* w1    = (const float*)d_in[2];
    const float* b1    = (const float*)d_in[3];
    const float* w2    = (const float*)d_in[4];
    const float* b2    = (const float*)d_in[5];
    const float* alpha = (const float*)d_in[6];
    const float* lap   = (const float*)d_in[7];
    float* out = (float*)d_out;

    float* ws    = (float*)d_ws;
    float* psum  = ws;                      // 8*16*256 = 32768
    float* pmax  = ws + 32768;              // 32768
    float* ptemp = ws + 65536;              // 8*8*16384 = 1048576

    k1_stats_temp<<<1024, 256, 0, stream>>>(x, dct_w, ptemp, psum, pmax);
    k2_fused<<<1024, 256, 0, stream>>>(x, ptemp, psum, pmax, w1, b1, w2, b2,
                                       alpha, lap, out);
}

// Round 8
// 75.429 us; speedup vs baseline: 6.3322x; 1.0477x over previous
//
#include <hip/hip_runtime.h>
#include <math.h>

#define C_ 256
#define R_ 16
#define B_ 8
#define H_ 128
#define W_ 128
#define HW_ (H_ * W_)
#define CG_ 8            // channel groups
#define CPG_ (C_ / CG_)  // 32 channels per group
#define NCHUNK_ 16       // pixel chunks per image (1024 px each)

typedef float f4_ __attribute__((ext_vector_type(4)));

__device__ __forceinline__ float sigmoidf_(float z) {
    return 1.0f / (1.0f + __expf(-z));
}

__device__ __forceinline__ int reflect_(int g) {
    if (g < 0) g = -g;
    if (g > 127) g = 254 - g;
    return g;
}

// Single x-pass. Grid 1024 = (b, chunk, cg). Block reads 32 channels x 1024
// pixels (128 KiB) as float4, computes its own m[c] slice from L2-resident
// dct_w, emits partial temp (per cg) and per-(b,chunk,c) sum/max partials.
__global__ void k1_stats_temp(const float* __restrict__ x, const float* __restrict__ dct_w,
                              float* __restrict__ ptemp,
                              float* __restrict__ psum, float* __restrict__ pmax) {
    __shared__ float sm_[CPG_];
    __shared__ float pmred[8][CPG_];
    __shared__ float lsum[16][CPG_ + 1];
    __shared__ float lmax[16][CPG_ + 1];
    int tid = threadIdx.x;
    int bid = blockIdx.x;
    int b = bid >> 7, chunk = (bid >> 3) & 15, cg = bid & 7;

    {   // m[c] slice for this channel group from L2-resident dct_w
        int c_l = tid & 31, oc = tid >> 5;
        const float* p = dct_w + cg * CPG_ + c_l;
        float pm = 0.0f;
        for (int k = 0; k < 32; ++k) pm += p[(oc * 32 + k) * C_];
        pmred[oc][c_l] = pm;
    }
    __syncthreads();
    if (tid < CPG_) {
        float t = 0.0f;
        for (int o = 0; o < 8; ++o) t += pmred[o][tid];
        sm_[tid] = t * (1.0f / C_);
    }
    __syncthreads();

    int pix = chunk * 1024 + tid * 4;
    const f4_* px = (const f4_*)(x + (size_t)(b * C_ + cg * CPG_) * HW_ + pix);
    int lane = tid & 63, wid = tid >> 6;
    int grp = (wid << 2) | (lane >> 4);
    bool writer = (lane & 15) == 0;

    f4_ acc = {0.0f, 0.0f, 0.0f, 0.0f};
#pragma unroll 4
    for (int c = 0; c < CPG_; ++c) {
        f4_ v = px[(size_t)c * (HW_ / 4)];
        float w = sm_[c];
        acc.x = fmaf(w, v.x, acc.x);
        acc.y = fmaf(w, v.y, acc.y);
        acc.z = fmaf(w, v.z, acc.z);
        acc.w = fmaf(w, v.w, acc.w);
        float s = (v.x + v.y) + (v.z + v.w);
        float mx = fmaxf(fmaxf(v.x, v.y), fmaxf(v.z, v.w));
        for (int mo = 8; mo >= 1; mo >>= 1) {
            s += __shfl_xor(s, mo, 16);
            mx = fmaxf(mx, __shfl_xor(mx, mo, 16));
        }
        if (writer) { lsum[grp][c] = s; lmax[grp][c] = mx; }
    }
    *(f4_*)(ptemp + (size_t)(cg * B_ + b) * HW_ + pix) = acc;
    __syncthreads();

    if (tid < CPG_) {
        float S = 0.0f, M = -3.402823466e+38f;
        for (int g = 0; g < 16; ++g) {
            S += lsum[g][tid];
            M = fmaxf(M, lmax[g][tid]);
        }
        psum[(size_t)(b * NCHUNK_ + chunk) * C_ + cg * CPG_ + tid] = S;
        pmax[(size_t)(b * NCHUNK_ + chunk) * C_ + cg * CPG_ + tid] = M;
    }
}

// Blocks 0..127: heat diffusion on 32x32 tiles, halo-3 (reflect + symmetric
// kernel => tile-local ghost compute exact). Tile load sums the 8 temp partials.
// Blocks 128..135: reduce stats partials -> SE MLP -> att.
#define TS_ 38
__global__ void k2_heat_fc(const float* __restrict__ ptemp,
                           const float* __restrict__ psum, const float* __restrict__ pmax,
                           const float* __restrict__ w1, const float* __restrict__ b1,
                           const float* __restrict__ w2, const float* __restrict__ b2,
                           const float* __restrict__ alphap, const float* __restrict__ lapp,
                           float* __restrict__ heat, float* __restrict__ att) {
    int tid = threadIdx.x;
    if (blockIdx.x < 128) {
        __shared__ float sA[TS_ * TS_], sB[TS_ * TS_];
        int b = blockIdx.x >> 4;
        int tile = blockIdx.x & 15;
        int tr = (tile >> 2) * 32, tc = (tile & 3) * 32;
        for (int i = tid; i < TS_ * TS_; i += 256) {
            int lh = i / TS_, lw = i % TS_;
            int gh = reflect_(tr + lh - 3);
            int gw = reflect_(tc + lw - 3);
            size_t a = (size_t)gh * W_ + gw + (size_t)b * HW_;
            float v = 0.0f;
#pragma unroll
            for (int cg = 0; cg < CG_; ++cg) v += ptemp[(size_t)cg * B_ * HW_ + a];
            sA[i] = v;
        }
        float alpha = *alphap;
        float l0 = lapp[0], l1 = lapp[1], l2 = lapp[2],
              l3 = lapp[3], l4 = lapp[4], l5 = lapp[5],
              l6 = lapp[6], l7 = lapp[7], l8 = lapp[8];
        __syncthreads();
#define DIFF(src, lh, lw)                                                              \
        fmaf(alpha,                                                                    \
             l0 * src[(lh - 1) * TS_ + lw - 1] + l1 * src[(lh - 1) * TS_ + lw] +       \
             l2 * src[(lh - 1) * TS_ + lw + 1] + l3 * src[lh * TS_ + lw - 1] +         \
             l4 * src[lh * TS_ + lw] + l5 * src[lh * TS_ + lw + 1] +                   \
             l6 * src[(lh + 1) * TS_ + lw - 1] + l7 * src[(lh + 1) * TS_ + lw] +       \
             l8 * src[(lh + 1) * TS_ + lw + 1],                                        \
             src[lh * TS_ + lw])
        for (int i = tid; i < 36 * 36; i += 256) {
            int lh = i / 36 + 1, lw = i % 36 + 1;
            sB[lh * TS_ + lw] = DIFF(sA, lh, lw);
        }
        __syncthreads();
        for (int i = tid; i < 34 * 34; i += 256) {
            int lh = i / 34 + 2, lw = i % 34 + 2;
            sA[lh * TS_ + lw] = DIFF(sB, lh, lw);
        }
        __syncthreads();
        float* hb = heat + b * HW_;
        for (int i = tid; i < 32 * 32; i += 256) {
            int lh = i / 32 + 3, lw = i % 32 + 3;
            float v = DIFF(sA, lh, lw);
            hb[(tr + lh - 3) * W_ + (tc + lw - 3)] = sigmoidf_(v);
        }
#undef DIFF
    } else {
        __shared__ float sa[C_], sx[C_], ha[R_], hm[R_];
        int b = blockIdx.x - 128;
        float S = 0.0f, M = -3.402823466e+38f;
        for (int ch = 0; ch < NCHUNK_; ++ch) {
            S += psum[(size_t)(b * NCHUNK_ + ch) * C_ + tid];
            M = fmaxf(M, pmax[(size_t)(b * NCHUNK_ + ch) * C_ + tid]);
        }
        sa[tid] = S * (1.0f / HW_);
        sx[tid] = M;
        __syncthreads();
        if (tid < 2 * R_) {
            int j = tid & (R_ - 1);
            bool isMax = tid >= R_;
            const float* y = isMax ? sx : sa;
            float s = b1[j];
            for (int c = 0; c < C_; ++c) s = fmaf(w1[j * C_ + c], y[c], s);
            s = fmaxf(s, 0.0f);
            (isMax ? hm : ha)[j] = s;
        }
        __syncthreads();
        float s1 = b2[tid], s2 = s1;
        for (int j = 0; j < R_; ++j) {
            float w = w2[tid * R_ + j];
            s1 = fmaf(w, ha[j], s1);
            s2 = fmaf(w, hm[j], s2);
        }
        att[b * C_ + tid] = sigmoidf_(s1) + sigmoidf_(s2);
    }
}

// out = x * sigmoid(att[b,c] * heat[b,hw]); nt-stores keep x resident in L3.
// Grid 4096: each block does half a (b,c) plane; inner loop fully unrolled
// (4 iters x 8 outstanding loads).
__global__ void k3_out(const float* __restrict__ x, const float* __restrict__ att,
                       const float* __restrict__ heat, float* __restrict__ out) {
    int bid = blockIdx.x;
    int bc = bid >> 1, half = bid & 1;
    int b = bc >> 8;
    float a = att[bc];
    size_t base = (size_t)bc * HW_ + half * (HW_ / 2);
    const f4_* px = (const f4_*)(x + base);
    const f4_* ph = (const f4_*)(heat + b * HW_ + half * (HW_ / 2));
    f4_* po = (f4_*)(out + base);
    int tid = threadIdx.x;
#pragma unroll
    for (int it = 0; it < HW_ / 8 / 256; ++it) {
        int i = it * 256 + tid;
        f4_ v = px[i];
        f4_ h = ph[i];
        f4_ r;
        r.x = v.x * sigmoidf_(a * h.x);
        r.y = v.y * sigmoidf_(a * h.y);
        r.z = v.z * sigmoidf_(a * h.z);
        r.w = v.w * sigmoidf_(a * h.w);
        __builtin_nontemporal_store(r, &po[i]);
    }
}

extern "C" void kernel_launch(void* const* d_in, const int* in_sizes, int n_in,
                              void* d_out, int out_size, void* d_ws, size_t ws_size,
                              hipStream_t stream) {
    const float* x     = (const float*)d_in[0];
    const float* dct_w = (const float*)d_in[1];
    const float* w1    = (const float*)d_in[2];
    const float* b1    = (const float*)d_in[3];
    const float* w2    = (const float*)d_in[4];
    const float* b2    = (const float*)d_in[5];
    const float* alpha = (const float*)d_in[6];
    const float* lap   = (const float*)d_in[7];
    float* out = (float*)d_out;

    float* ws    = (float*)d_ws;
    float* psum  = ws;                      // 8*16*256 = 32768
    float* pmax  = ws + 32768;              // 32768
    float* att   = ws + 65536;              // 2048
    float* heat  = ws + 69632;              // 131072
    float* ptemp = ws + 200704;             // 8*8*16384 = 1048576

    k1_stats_temp<<<1024, 256, 0, stream>>>(x, dct_w, ptemp, psum, pmax);
    k2_heat_fc<<<136, 256, 0, stream>>>(ptemp, psum, pmax, w1, b1, w2, b2, alpha, lap, heat, att);
    k3_out<<<4096, 256, 0, stream>>>(x, att, heat, out);
}

// Round 9
// 74.272 us; speedup vs baseline: 6.4309x; 1.0156x over previous
//
#include <hip/hip_runtime.h>
#include <math.h>

#define C_ 256
#define R_ 16
#define B_ 8
#define H_ 128
#define W_ 128
#define HW_ (H_ * W_)
#define CG_ 8            // channel groups
#define CPG_ (C_ / CG_)  // 32 channels per group
#define NCHUNK_ 16       // pixel chunks per image (1024 px each)

typedef float f4_ __attribute__((ext_vector_type(4)));

__device__ __forceinline__ float sigmoidf_(float z) {
    return 1.0f / (1.0f + __expf(-z));
}

__device__ __forceinline__ int reflect_(int g) {
    if (g < 0) g = -g;
    if (g > 127) g = 254 - g;
    return g;
}

// Single x-pass. Grid 1024 = (b, chunk, cg). Block reads 32 channels x 1024
// pixels (128 KiB) as float4. Stats via batched LDS partials (no per-iteration
// shuffle chains): each thread writes hsum/hmax per channel; one reduce per
// 16-channel half. Temp accumulated in registers as before.
__global__ void k1_stats_temp(const float* __restrict__ x, const float* __restrict__ dct_w,
                              float* __restrict__ ptemp,
                              float* __restrict__ psum, float* __restrict__ pmax) {
    __shared__ float sm_[CPG_];
    __shared__ float pmred[8][CPG_];
    __shared__ float ls[16][260];   // stride 260: reduce-phase banks 2-way max
    __shared__ float lm[16][260];
    int tid = threadIdx.x;
    int bid = blockIdx.x;
    int b = bid >> 7, chunk = (bid >> 3) & 15, cg = bid & 7;

    {   // m[c] slice for this channel group from L2-resident dct_w
        int c_l = tid & 31, oc = tid >> 5;
        const float* p = dct_w + cg * CPG_ + c_l;
        float pm = 0.0f;
        for (int k = 0; k < 32; ++k) pm += p[(oc * 32 + k) * C_];
        pmred[oc][c_l] = pm;
    }
    __syncthreads();
    if (tid < CPG_) {
        float t = 0.0f;
        for (int o = 0; o < 8; ++o) t += pmred[o][tid];
        sm_[tid] = t * (1.0f / C_);
    }
    __syncthreads();

    int pix = chunk * 1024 + tid * 4;
    const f4_* px = (const f4_*)(x + (size_t)(b * C_ + cg * CPG_) * HW_ + pix);
    int statbase = (b * NCHUNK_ + chunk) * C_ + cg * CPG_;

    f4_ acc = {0.0f, 0.0f, 0.0f, 0.0f};
    for (int half = 0; half < 2; ++half) {
        int c0 = half * 16;
#pragma unroll 8
        for (int cc = 0; cc < 16; ++cc) {
            int c = c0 + cc;
            f4_ v = px[(size_t)c * (HW_ / 4)];
            float w = sm_[c];
            acc.x = fmaf(w, v.x, acc.x);
            acc.y = fmaf(w, v.y, acc.y);
            acc.z = fmaf(w, v.z, acc.z);
            acc.w = fmaf(w, v.w, acc.w);
            ls[cc][tid] = (v.x + v.y) + (v.z + v.w);
            lm[cc][tid] = fmaxf(fmaxf(v.x, v.y), fmaxf(v.z, v.w));
        }
        __syncthreads();
        {   // batched reduce: 16 threads per channel, 16 reads each, then 4 shuffles
            int c_l = tid >> 4, s = tid & 15;
            float S = 0.0f, M = -3.402823466e+38f;
#pragma unroll
            for (int j = 0; j < 16; ++j) {
                S += ls[c_l][s + 16 * j];
                M = fmaxf(M, lm[c_l][s + 16 * j]);
            }
            for (int mo = 8; mo >= 1; mo >>= 1) {
                S += __shfl_xor(S, mo, 16);
                M = fmaxf(M, __shfl_xor(M, mo, 16));
            }
            if (s == 0) {
                psum[statbase + c0 + c_l] = S;
                pmax[statbase + c0 + c_l] = M;
            }
        }
        __syncthreads();   // ls/lm reused by next half
    }
    *(f4_*)(ptemp + (size_t)(cg * B_ + b) * HW_ + pix) = acc;
}

// Blocks 0..127: heat diffusion on 32x32 tiles, halo-3 (reflect + symmetric
// kernel => tile-local ghost compute exact). Tile load sums the 8 temp partials.
// Blocks 128..135: reduce stats partials -> SE MLP -> att.
#define TS_ 38
__global__ void k2_heat_fc(const float* __restrict__ ptemp,
                           const float* __restrict__ psum, const float* __restrict__ pmax,
                           const float* __restrict__ w1, const float* __restrict__ b1,
                           const float* __restrict__ w2, const float* __restrict__ b2,
                           const float* __restrict__ alphap, const float* __restrict__ lapp,
                           float* __restrict__ heat, float* __restrict__ att) {
    int tid = threadIdx.x;
    if (blockIdx.x < 128) {
        __shared__ float sA[TS_ * TS_], sB[TS_ * TS_];
        int b = blockIdx.x >> 4;
        int tile = blockIdx.x & 15;
        int tr = (tile >> 2) * 32, tc = (tile & 3) * 32;
        for (int i = tid; i < TS_ * TS_; i += 256) {
            int lh = i / TS_, lw = i % TS_;
            int gh = reflect_(tr + lh - 3);
            int gw = reflect_(tc + lw - 3);
            size_t a = (size_t)gh * W_ + gw + (size_t)b * HW_;
            float v = 0.0f;
#pragma unroll
            for (int cg = 0; cg < CG_; ++cg) v += ptemp[(size_t)cg * B_ * HW_ + a];
            sA[i] = v;
        }
        float alpha = *alphap;
        float l0 = lapp[0], l1 = lapp[1], l2 = lapp[2],
              l3 = lapp[3], l4 = lapp[4], l5 = lapp[5],
              l6 = lapp[6], l7 = lapp[7], l8 = lapp[8];
        __syncthreads();
#define DIFF(src, lh, lw)                                                              \
        fmaf(alpha,                                                                    \
             l0 * src[(lh - 1) * TS_ + lw - 1] + l1 * src[(lh - 1) * TS_ + lw] +       \
             l2 * src[(lh - 1) * TS_ + lw + 1] + l3 * src[lh * TS_ + lw - 1] +         \
             l4 * src[lh * TS_ + lw] + l5 * src[lh * TS_ + lw + 1] +                   \
             l6 * src[(lh + 1) * TS_ + lw - 1] + l7 * src[(lh + 1) * TS_ + lw] +       \
             l8 * src[(lh + 1) * TS_ + lw + 1],                                        \
             src[lh * TS_ + lw])
        for (int i = tid; i < 36 * 36; i += 256) {
            int lh = i / 36 + 1, lw = i % 36 + 1;
            sB[lh * TS_ + lw] = DIFF(sA, lh, lw);
        }
        __syncthreads();
        for (int i = tid; i < 34 * 34; i += 256) {
            int lh = i / 34 + 2, lw = i % 34 + 2;
            sA[lh * TS_ + lw] = DIFF(sB, lh, lw);
        }
        __syncthreads();
        float* hb = heat + b * HW_;
        for (int i = tid; i < 32 * 32; i += 256) {
            int lh = i / 32 + 3, lw = i % 32 + 3;
            float v = DIFF(sA, lh, lw);
            hb[(tr + lh - 3) * W_ + (tc + lw - 3)] = sigmoidf_(v);
        }
#undef DIFF
    } else {
        __shared__ float sa[C_], sx[C_], ha[R_], hm[R_];
        int b = blockIdx.x - 128;
        float S = 0.0f, M = -3.402823466e+38f;
        for (int ch = 0; ch < NCHUNK_; ++ch) {
            S += psum[(size_t)(b * NCHUNK_ + ch) * C_ + tid];
            M = fmaxf(M, pmax[(size_t)(b * NCHUNK_ + ch) * C_ + tid]);
        }
        sa[tid] = S * (1.0f / HW_);
        sx[tid] = M;
        __syncthreads();
        if (tid < 2 * R_) {
            int j = tid & (R_ - 1);
            bool isMax = tid >= R_;
            const float* y = isMax ? sx : sa;
            float s = b1[j];
            for (int c = 0; c < C_; ++c) s = fmaf(w1[j * C_ + c], y[c], s);
            s = fmaxf(s, 0.0f);
            (isMax ? hm : ha)[j] = s;
        }
        __syncthreads();
        float s1 = b2[tid], s2 = s1;
        for (int j = 0; j < R_; ++j) {
            float w = w2[tid * R_ + j];
            s1 = fmaf(w, ha[j], s1);
            s2 = fmaf(w, hm[j], s2);
        }
        att[b * C_ + tid] = sigmoidf_(s1) + sigmoidf_(s2);
    }
}

// out = x * sigmoid(att[b,c] * heat[b,hw]); nt-stores keep x resident in L3.
// Grid 4096: each block does half a (b,c) plane.
__global__ void k3_out(const float* __restrict__ x, const float* __restrict__ att,
                       const float* __restrict__ heat, float* __restrict__ out) {
    int bid = blockIdx.x;
    int bc = bid >> 1, half = bid & 1;
    int b = bc >> 8;
    float a = att[bc];
    size_t base = (size_t)bc * HW_ + half * (HW_ / 2);
    const f4_* px = (const f4_*)(x + base);
    const f4_* ph = (const f4_*)(heat + b * HW_ + half * (HW_ / 2));
    f4_* po = (f4_*)(out + base);
    int tid = threadIdx.x;
#pragma unroll
    for (int it = 0; it < HW_ / 8 / 256; ++it) {
        int i = it * 256 + tid;
        f4_ v = px[i];
        f4_ h = ph[i];
        f4_ r;
        r.x = v.x * sigmoidf_(a * h.x);
        r.y = v.y * sigmoidf_(a * h.y);
        r.z = v.z * sigmoidf_(a * h.z);
        r.w = v.w * sigmoidf_(a * h.w);
        __builtin_nontemporal_store(r, &po[i]);
    }
}

extern "C" void kernel_launch(void* const* d_in, const int* in_sizes, int n_in,
                              void* d_out, int out_size, void* d_ws, size_t ws_size,
                              hipStream_t stream) {
    const float* x     = (const float*)d_in[0];
    const float* dct_w = (const float*)d_in[1];
    const float* w1    = (const float*)d_in[2];
    const float* b1    = (const float*)d_in[3];
    const float* w2    = (const float*)d_in[4];
    const float* b2    = (const float*)d_in[5];
    const float* alpha = (const float*)d_in[6];
    const float* lap   = (const float*)d_in[7];
    float* out = (float*)d_out;

    float* ws    = (float*)d_ws;
    float* psum  = ws;                      // 8*16*256 = 32768
    float* pmax  = ws + 32768;              // 32768
    float* att   = ws + 65536;              // 2048
    float* heat  = ws + 69632;              // 131072
    float* ptemp = ws + 200704;             // 8*8*16384 = 1048576

    k1_stats_temp<<<1024, 256, 0, stream>>>(x, dct_w, ptemp, psum, pmax);
    k2_heat_fc<<<136, 256, 0, stream>>>(ptemp, psum, pmax, w1, b1, w2, b2, alpha, lap, heat, att);
    k3_out<<<4096, 256, 0, stream>>>(x, att, heat, out);
}